// Round 2
// baseline (6548.102 us; speedup 1.0000x reference)
//
#include <hip/hip_runtime.h>

// RecNet: 100-step recurrent LIF SNN + LI readout.
// Numerics: the spike threshold makes the dynamics chaotic under summation-order
// noise -> compute the exact trajectory (fp64 accumulation everywhere).
//   K1 gemm_in : cin[t,b,h] = x[t,b,:].w_in[h,:]  fp64-acc, cin stored double
//   per step t: stepA (elementwise LIF, fp64) ; stepB (rec partials fp64 + readout fp64)
// Stream ordering provides inter-step dependencies.

#define TT    100
#define BATCH 512
#define FDIM  784
#define HDIM  512
#define ODIM  10
#define NSTATE (BATCH * HDIM)   // 262144

// DT*TAU_MEM_INV and DT*TAU_SYN_INV round to exactly these doubles
#define DTM 0.1
#define DTS 0.2

// ---------------- K1: C[m][n] = sum_k A[m][k]*B[n][k], fp64 acc ----------------
// M=51200 K=784 N=512. 64x64 tile, BK=16 (784=49*16), 256 thr, 4x4 double acc.
__global__ __launch_bounds__(256) void gemm_in_kernel(const float* __restrict__ A,
                                                      const float* __restrict__ B,
                                                      double* __restrict__ C) {
  __shared__ float As[16][68];
  __shared__ float Bs[16][68];
  const int tid = threadIdx.x;
  const int tn = tid & 15;          // n quad (fast -> coalesced C stores)
  const int tm = tid >> 4;          // m quad
  const int m0 = blockIdx.x << 6;
  const int n0 = blockIdx.y << 6;
  const int lrow = tid >> 2;        // 0..63
  const int lkc  = (tid & 3) << 2;  // 0,4,8,12

  double acc[4][4] = {};

  for (int kt = 0; kt < 49; ++kt) {
    __syncthreads();
    const float4 a = *(const float4*)(A + (size_t)(m0 + lrow) * FDIM + kt * 16 + lkc);
    As[lkc + 0][lrow] = a.x; As[lkc + 1][lrow] = a.y;
    As[lkc + 2][lrow] = a.z; As[lkc + 3][lrow] = a.w;
    const float4 b = *(const float4*)(B + (size_t)(n0 + lrow) * FDIM + kt * 16 + lkc);
    Bs[lkc + 0][lrow] = b.x; Bs[lkc + 1][lrow] = b.y;
    Bs[lkc + 2][lrow] = b.z; Bs[lkc + 3][lrow] = b.w;
    __syncthreads();
#pragma unroll
    for (int kk = 0; kk < 16; ++kk) {
      const float4 af = *(const float4*)&As[kk][tm << 2];
      const float4 bf = *(const float4*)&Bs[kk][tn << 2];
      const double am[4] = {(double)af.x, (double)af.y, (double)af.z, (double)af.w};
      const double bn[4] = {(double)bf.x, (double)bf.y, (double)bf.z, (double)bf.w};
#pragma unroll
      for (int i = 0; i < 4; ++i)
#pragma unroll
        for (int j = 0; j < 4; ++j) acc[i][j] += am[i] * bn[j];
    }
  }
#pragma unroll
  for (int i = 0; i < 4; ++i) {
    double* crow = C + (size_t)(m0 + (tm << 2) + i) * HDIM + n0 + (tn << 2);
    *(double2*)(crow)     = make_double2(acc[i][0], acc[i][1]);
    *(double2*)(crow + 2) = make_double2(acc[i][2], acc[i][3]);
  }
}

// ---------------- stepA: elementwise LIF state update (fp64) ----------------
// 512 blocks x 256 thr, 2 elements (double2) per thread.
__global__ __launch_bounds__(256) void stepA_kernel(const double* __restrict__ cin_t,
                                                    const double* __restrict__ rp,
                                                    double* __restrict__ v,
                                                    double* __restrict__ i_,
                                                    float* __restrict__ z) {
  const int e = ((blockIdx.x << 8) + threadIdx.x) << 1;
  const double2 vv = *(const double2*)(v + e);
  const double2 ii = *(const double2*)(i_ + e);
  const double2 cc = *(const double2*)(cin_t + e);
  const double2 r0 = *(const double2*)(rp + e);
  const double2 r1 = *(const double2*)(rp + e + NSTATE);
  const double2 r2 = *(const double2*)(rp + e + 2 * NSTATE);
  const double2 r3 = *(const double2*)(rp + e + 3 * NSTATE);

  double2 vn, in_;
  float2 zn;
#define STEP1(c, zc)                                                    \
  {                                                                     \
    const double rec  = ((r0.c + r1.c) + r2.c) + r3.c;                  \
    const double vdec = vv.c + DTM * ((0.0 - vv.c) + ii.c);             \
    const double idec = ii.c - DTS * ii.c;                              \
    const bool   sp   = (vdec - 1.0) > 0.0;                             \
    vn.c  = sp ? 0.0 : vdec;                                            \
    in_.c = (idec + cc.c) + rec;                                        \
    zn.zc = sp ? 1.0f : 0.0f;                                           \
  }
  STEP1(x, x) STEP1(y, y)
#undef STEP1

  *(double2*)(v + e)  = vn;
  *(double2*)(i_ + e) = in_;
  *(float2*)(z + e)   = zn;
}

// ---------------- stepB: rec partials (fp64) + readout (fp64) ----------------
// blocks 0..255: rp[ks][b][h] = sum_{k in ks-slice} z[b][k]*w_rec[h][k]
//   tile 64h x 64b x 128k, 256 thr, 4x4 double acc.
// blocks 256..259: y = z @ w_out^T, LI update, out(t).
__global__ __launch_bounds__(256) void stepB_kernel(const float* __restrict__ w_rec,
                                                    const float* __restrict__ z,
                                                    double* __restrict__ rp,
                                                    const float* __restrict__ w_out,
                                                    double* __restrict__ lv,
                                                    double* __restrict__ li,
                                                    float* __restrict__ out_t) {
  __shared__ float ws[128][68];
  __shared__ float zs[128][68];
  if (blockIdx.x < 256) {
    const int ks = blockIdx.x & 3;
    const int hb = (blockIdx.x >> 2) & 7;
    const int bb = blockIdx.x >> 5;
    const int h0 = hb << 6, b0 = bb << 6, k0 = ks << 7;
    const int tid = threadIdx.x;
#pragma unroll
    for (int s = 0; s < 8; ++s) {
      const int idx = tid + (s << 8);   // 0..2047 float4 slots
      const int row = idx >> 5;         // 0..63
      const int kc  = (idx & 31) << 2;  // 0..124
      const float4 a = *(const float4*)(w_rec + (size_t)(h0 + row) * HDIM + k0 + kc);
      ws[kc + 0][row] = a.x; ws[kc + 1][row] = a.y;
      ws[kc + 2][row] = a.z; ws[kc + 3][row] = a.w;
      const float4 zb = *(const float4*)(z + (size_t)(b0 + row) * HDIM + k0 + kc);
      zs[kc + 0][row] = zb.x; zs[kc + 1][row] = zb.y;
      zs[kc + 2][row] = zb.z; zs[kc + 3][row] = zb.w;
    }
    __syncthreads();
    const int th = tid & 15;   // h quad (fast -> coalesced rp stores)
    const int tb = tid >> 4;   // b quad
    double acc[4][4] = {};
#pragma unroll 4
    for (int kk = 0; kk < 128; ++kk) {
      const float4 af = *(const float4*)&ws[kk][th << 2];
      const float4 qf = *(const float4*)&zs[kk][tb << 2];
      const double aw[4] = {(double)af.x, (double)af.y, (double)af.z, (double)af.w};
      const double qd[4] = {(double)qf.x, (double)qf.y, (double)qf.z, (double)qf.w};
#pragma unroll
      for (int jb = 0; jb < 4; ++jb)
#pragma unroll
        for (int ih = 0; ih < 4; ++ih) acc[jb][ih] += qd[jb] * aw[ih];
    }
#pragma unroll
    for (int jb = 0; jb < 4; ++jb) {
      double* dst = rp + (size_t)ks * NSTATE +
                    (size_t)(b0 + (tb << 2) + jb) * HDIM + h0 + (th << 2);
      *(double2*)(dst)     = make_double2(acc[jb][0], acc[jb][1]);
      *(double2*)(dst + 2) = make_double2(acc[jb][2], acc[jb][3]);
    }
  } else {
    // readout: 4 blocks * 256 thr = 1024 = 512 b * 2 halves (5 outputs each)
    const int gt = ((blockIdx.x - 256) << 8) + threadIdx.x;
    const int b  = gt >> 1;
    const int o0 = (gt & 1) * 5;
    const float* zrow = z + (size_t)b * HDIM;
    double acc[5] = {0.0, 0.0, 0.0, 0.0, 0.0};
#pragma unroll 2
    for (int k4 = 0; k4 < 128; ++k4) {
      const float4 zv = *(const float4*)(zrow + (k4 << 2));
#pragma unroll
      for (int oo = 0; oo < 5; ++oo) {
        const float4 w = *(const float4*)(w_out + (size_t)(o0 + oo) * HDIM + (k4 << 2));
        acc[oo] += ((double)zv.x * (double)w.x + (double)zv.y * (double)w.y) +
                   ((double)zv.z * (double)w.z + (double)zv.w * (double)w.w);
      }
    }
#pragma unroll
    for (int oo = 0; oo < 5; ++oo) {
      const int io = b * ODIM + o0 + oo;
      const double lvv = lv[io];
      const double lii = li[io];
      const double lvn = lvv + DTM * ((0.0 - lvv) + lii);   // uses OLD li
      const double lin = (lii - DTS * lii) + acc[oo];
      out_t[io] = (float)lvn;
      lv[io] = lvn;
      li[io] = lin;
    }
  }
}

extern "C" void kernel_launch(void* const* d_in, const int* in_sizes, int n_in,
                              void* d_out, int out_size, void* d_ws, size_t ws_size,
                              hipStream_t stream) {
  const float* x     = (const float*)d_in[0];   // [100,512,784]
  const float* w_in  = (const float*)d_in[1];   // [512,784]
  const float* w_rec = (const float*)d_in[2];   // [512,512]
  const float* w_out = (const float*)d_in[3];   // [10,512]
  float* out = (float*)d_out;                   // [100,512,10] fp32

  const size_t CIN = (size_t)TT * BATCH * HDIM;   // 26,214,400 doubles
  double* cin = (double*)d_ws;
  double* v   = cin + CIN;
  double* i_  = v + NSTATE;
  double* rp  = i_ + NSTATE;           // 4 * NSTATE
  double* lv  = rp + 4ull * NSTATE;
  double* li  = lv + (size_t)BATCH * ODIM;
  float*  z   = (float*)(li + (size_t)BATCH * ODIM);

  const size_t state_bytes = (2ull * NSTATE + 4ull * NSTATE + 2ull * BATCH * ODIM) * sizeof(double)
                           + (size_t)NSTATE * sizeof(float);
  const size_t need_bytes = CIN * sizeof(double) + state_bytes;
  if (ws_size < need_bytes) {
    // visible sentinel: identifiable failure mode (absmax ~3e38)
    hipMemsetAsync(d_out, 0x7F, (size_t)out_size * sizeof(float), stream);
    return;
  }

  // zero v,i,rp,lv,li,z (contiguous after cin) every call — deterministic
  hipMemsetAsync(v, 0, state_bytes, stream);

  gemm_in_kernel<<<dim3(800, 8), 256, 0, stream>>>(x, w_in, cin);

  for (int t = 0; t < TT; ++t) {
    stepA_kernel<<<512, 256, 0, stream>>>(cin + (size_t)t * NSTATE, rp, v, i_, z);
    stepB_kernel<<<260, 256, 0, stream>>>(w_rec, z, rp, w_out, lv, li,
                                          out + (size_t)t * BATCH * ODIM);
  }
}

// Round 3
// 1207.309 us; speedup vs baseline: 5.4237x; 5.4237x over previous
//
#include <hip/hip_runtime.h>

// RecNet: 100-step recurrent LIF SNN + LI readout. Exact fp64 trajectory.
//   K1 gemm_in : cin[t,b,h] = x[t,b,:].w_in[h,:]  fp64-acc (matches np fp64 ref)
//   K2 lif     : persistent, one block per batch element, all 100 steps.
//                Spikes are binary+sparse -> rec matvec = gather of fired rows
//                of wrt (=W_rec^T), fp64 adds (order-independent, exact values).
// Per-batch independence => no cross-block communication at all.

#define TT    100
#define BATCH 512
#define FDIM  784
#define HDIM  512
#define ODIM  10
#define NSTATE (BATCH * HDIM)

// DT*TAU_MEM_INV / DT*TAU_SYN_INV round in fp64 exactly to 0.1 / 0.2
#define DTM 0.1
#define DTS 0.2

// ---------------- K1: C[m][n] = sum_k A[m][k]*B[n][k], fp64 acc ----------------
__global__ __launch_bounds__(256) void gemm_in_kernel(const float* __restrict__ A,
                                                      const float* __restrict__ B,
                                                      double* __restrict__ C) {
  __shared__ float As[16][68];
  __shared__ float Bs[16][68];
  const int tid = threadIdx.x;
  const int tn = tid & 15;
  const int tm = tid >> 4;
  const int m0 = blockIdx.x << 6;
  const int n0 = blockIdx.y << 6;
  const int lrow = tid >> 2;
  const int lkc  = (tid & 3) << 2;

  double acc[4][4] = {};

  for (int kt = 0; kt < 49; ++kt) {
    __syncthreads();
    const float4 a = *(const float4*)(A + (size_t)(m0 + lrow) * FDIM + kt * 16 + lkc);
    As[lkc + 0][lrow] = a.x; As[lkc + 1][lrow] = a.y;
    As[lkc + 2][lrow] = a.z; As[lkc + 3][lrow] = a.w;
    const float4 b = *(const float4*)(B + (size_t)(n0 + lrow) * FDIM + kt * 16 + lkc);
    Bs[lkc + 0][lrow] = b.x; Bs[lkc + 1][lrow] = b.y;
    Bs[lkc + 2][lrow] = b.z; Bs[lkc + 3][lrow] = b.w;
    __syncthreads();
#pragma unroll
    for (int kk = 0; kk < 16; ++kk) {
      const float4 af = *(const float4*)&As[kk][tm << 2];
      const float4 bf = *(const float4*)&Bs[kk][tn << 2];
      const double am[4] = {(double)af.x, (double)af.y, (double)af.z, (double)af.w};
      const double bn[4] = {(double)bf.x, (double)bf.y, (double)bf.z, (double)bf.w};
#pragma unroll
      for (int i = 0; i < 4; ++i)
#pragma unroll
        for (int j = 0; j < 4; ++j) acc[i][j] += am[i] * bn[j];
    }
  }
#pragma unroll
  for (int i = 0; i < 4; ++i) {
    double* crow = C + (size_t)(m0 + (tm << 2) + i) * HDIM + n0 + (tn << 2);
    *(double2*)(crow)     = make_double2(acc[i][0], acc[i][1]);
    *(double2*)(crow + 2) = make_double2(acc[i][2], acc[i][3]);
  }
}

// ---------------- transpose w_rec [512][512] -> wrt [k][h] ----------------
__global__ __launch_bounds__(256) void transpose_kernel(const float* __restrict__ src,
                                                        float* __restrict__ dst) {
  __shared__ float tile[32][33];
  const int bx = blockIdx.x & 15, by = blockIdx.x >> 4;
  const int tx = threadIdx.x & 31, ty = threadIdx.x >> 5;
  const int x = (bx << 5) + tx;
#pragma unroll
  for (int s = 0; s < 32; s += 8)
    tile[ty + s][tx] = src[(size_t)((by << 5) + ty + s) * HDIM + x];
  __syncthreads();
  const int xo = (by << 5) + tx;
#pragma unroll
  for (int s = 0; s < 32; s += 8)
    dst[(size_t)((bx << 5) + ty + s) * HDIM + xo] = tile[tx][ty + s];
}

// ---------------- w_out [10][512] -> wot [k][16] (cols 10..15 stay zero) -------
__global__ __launch_bounds__(256) void wot_kernel(const float* __restrict__ w_out,
                                                  float* __restrict__ wot) {
  const int k = (blockIdx.x << 8) + threadIdx.x;  // 0..511
#pragma unroll
  for (int o = 0; o < ODIM; ++o) wot[(k << 4) + o] = w_out[(size_t)o * HDIM + k];
}

// ---------------- K2: persistent LIF+LI, one block per batch element ----------
// 256 threads, thread j owns h0=j, h1=j+256. v,i in regs (fp64). Per step:
//  (a) spikes from old v,i; decay
//  (b) i += cin[t] + gather over PREVIOUS step's fired list (rec uses z(t-1))
//  (c) ballot -> masks -> compact current fired list
//  (d) y(t) gathered from wot over current list; LI update; out write
__global__ __launch_bounds__(256) void lif_kernel(const double* __restrict__ cin,
                                                  const float* __restrict__ wrt,
                                                  const float* __restrict__ wot,
                                                  float* __restrict__ out) {
  const int b = blockIdx.x;
  const int tid = threadIdx.x;
  const int h0 = tid, h1 = tid + 256;

  __shared__ unsigned long long masks[8];
  __shared__ int offs[9];                       // offs[8] = nfire (persists 1 step)
  __shared__ __align__(8) unsigned short list[528];
  __shared__ double ypart[256];

  if (tid == 0) offs[8] = 0;                    // empty list at t=0
  __syncthreads();

  double v0 = 0.0, v1 = 0.0, i0 = 0.0, i1 = 0.0;
  double lv = 0.0, li = 0.0;                    // live in threads 0..9

  const double* cinb = cin + (size_t)b * HDIM;
  float* outb = out + (size_t)b * ODIM;

  for (int t = 0; t < TT; ++t) {
    // (a) LIF: spikes from old state, then decay
    const double vd0 = v0 + DTM * ((0.0 - v0) + i0);
    const double vd1 = v1 + DTM * ((0.0 - v1) + i1);
    const bool s0 = (vd0 - 1.0) > 0.0;
    const bool s1 = (vd1 - 1.0) > 0.0;
    v0 = s0 ? 0.0 : vd0;
    v1 = s1 ? 0.0 : vd1;
    i0 = i0 - DTS * i0;
    i1 = i1 - DTS * i1;

    // issue cin loads early (consumed after gather)
    const double c0 = cinb[(size_t)t * NSTATE + h0];
    const double c1 = cinb[(size_t)t * NSTATE + h1];

    // (b) rec gather over PREVIOUS step's fired list (z(t-1) @ W_rec^T)
    {
      const int nf = offs[8];
      const int nfp = (nf + 3) & ~3;            // list padded with k=512 (zero row)
      if (nfp > 0) {
        float A0[4], A1[4], B0[4] = {}, B1[4] = {};
#define LOADG(base, X0, X1)                                                   \
        do {                                                                  \
          const unsigned long long le = *(const unsigned long long*)&list[base]; \
          const int k0 = (int)(le & 0xffffu), k1 = (int)((le >> 16) & 0xffffu); \
          const int k2 = (int)((le >> 32) & 0xffffu), k3 = (int)(le >> 48);   \
          X0[0] = wrt[(k0 << 9) + h0]; X1[0] = wrt[(k0 << 9) + h1];           \
          X0[1] = wrt[(k1 << 9) + h0]; X1[1] = wrt[(k1 << 9) + h1];           \
          X0[2] = wrt[(k2 << 9) + h0]; X1[2] = wrt[(k2 << 9) + h1];           \
          X0[3] = wrt[(k3 << 9) + h0]; X1[3] = wrt[(k3 << 9) + h1];           \
        } while (0)
        LOADG(0, A0, A1);
        for (int g = 0; g < nfp; g += 4) {
          if (g + 4 < nfp) LOADG(g + 4, B0, B1);
          i0 += (double)A0[0]; i1 += (double)A1[0];
          i0 += (double)A0[1]; i1 += (double)A1[1];
          i0 += (double)A0[2]; i1 += (double)A1[2];
          i0 += (double)A0[3]; i1 += (double)A1[3];
#pragma unroll
          for (int j = 0; j < 4; ++j) { A0[j] = B0[j]; A1[j] = B1[j]; }
        }
#undef LOADG
      }
    }
    i0 += c0;
    i1 += c1;

    __syncthreads();  // B1: gathers done reading list/offs before overwrite

    // (c) ballot + compact current spikes
    {
      const unsigned long long m0 = __ballot(s0);
      const unsigned long long m1 = __ballot(s1);
      const int w = tid >> 6;
      if ((tid & 63) == 0) { masks[w] = m0; masks[4 + w] = m1; }
    }
    __syncthreads();  // B2
    if (tid == 0) {
      int r = 0;
#pragma unroll
      for (int q = 0; q < 8; ++q) { offs[q] = r; r += __popcll(masks[q]); }
      offs[8] = r;
    }
    __syncthreads();  // B3
    if (tid < 8) {
      unsigned long long m = masks[tid];
      int o = offs[tid];
      const int base = tid << 6;
      while (m) {
        list[o++] = (unsigned short)(base + __builtin_ctzll(m));
        m &= m - 1;
      }
    }
    if (tid < 4) list[offs[8] + tid] = 512;     // pad for group-of-4 reads
    __syncthreads();  // B4

    // (d) readout y(t) = sum over current fired k of wot[k][o]
    {
      const int o = tid & 15, q = tid >> 4;     // 16 chunks x 16 "outputs" (10 real)
      const int nfc = offs[8];
      double yp = 0.0;
      int kk = q;
      if (kk < nfc) {
        float f = wot[((int)list[kk] << 4) + o];
        for (kk += 16; kk < nfc; kk += 16) {
          const float fn = wot[((int)list[kk] << 4) + o];
          yp += (double)f;
          f = fn;
        }
        yp += (double)f;
      }
      ypart[(o << 4) + q] = yp;
    }
    __syncthreads();  // B5
    if (tid < ODIM) {
      double y = 0.0;
      const double* yr = &ypart[tid << 4];
#pragma unroll
      for (int q = 0; q < 16; ++q) y += yr[q];
      const double lvn = lv + DTM * ((0.0 - lv) + li);   // uses OLD li
      li = (li - DTS * li) + y;
      lv = lvn;
      outb[(size_t)t * (BATCH * ODIM) + tid] = (float)lvn;
    }
  }
}

extern "C" void kernel_launch(void* const* d_in, const int* in_sizes, int n_in,
                              void* d_out, int out_size, void* d_ws, size_t ws_size,
                              hipStream_t stream) {
  const float* x     = (const float*)d_in[0];   // [100,512,784]
  const float* w_in  = (const float*)d_in[1];   // [512,784]
  const float* w_rec = (const float*)d_in[2];   // [512,512]
  const float* w_out = (const float*)d_in[3];   // [10,512]
  float* out = (float*)d_out;                   // [100,512,10] fp32

  const size_t CIN = (size_t)TT * BATCH * HDIM;       // 26,214,400 doubles
  double* cin = (double*)d_ws;
  float* wrt = (float*)(cin + CIN);                   // [513][512], row 512 = zeros
  float* wot = wrt + 513 * 512;                       // [513][16],  row 512 + cols 10..15 zero

  const size_t aux_floats = 513ull * 512 + 513ull * 16;
  const size_t need_bytes = CIN * sizeof(double) + aux_floats * sizeof(float);
  if (ws_size < need_bytes) {
    hipMemsetAsync(d_out, 0x7F, (size_t)out_size * sizeof(float), stream);
    return;
  }

  hipMemsetAsync(wrt, 0, aux_floats * sizeof(float), stream);
  transpose_kernel<<<256, 256, 0, stream>>>(w_rec, wrt);
  wot_kernel<<<2, 256, 0, stream>>>(w_out, wot);
  gemm_in_kernel<<<dim3(800, 8), 256, 0, stream>>>(x, w_in, cin);
  lif_kernel<<<BATCH, 256, 0, stream>>>(cin, wrt, wot, out);
}

// Round 4
// 1110.926 us; speedup vs baseline: 5.8943x; 1.0868x over previous
//
#include <hip/hip_runtime.h>

// RecNet: 100-step recurrent LIF SNN + LI readout. Exact fp64 trajectory.
//   K1 gemm_in : cin[t,b,h] = x[t,b,:].w_in[h,:]  fp64-acc. LDS staged as double
//                (cvt once at staging), 128m x 64n tile, 8x4 fp64 micro-tile.
//   K2 lif     : persistent, one block per batch element, spike-sparse gather.

#define TT    100
#define BATCH 512
#define FDIM  784
#define HDIM  512
#define ODIM  10
#define NSTATE (BATCH * HDIM)

// DT*TAU_MEM_INV / DT*TAU_SYN_INV round in fp64 exactly to 0.1 / 0.2
#define DTM 0.1
#define DTS 0.2

// ---------------- K1: C[m][n] = sum_k A[m][k]*B[n][k], fp64 acc ----------------
// M=51200 K=784 N=512. Tile 128m x 64n, BK=16 (784=49*16), 256 thr, 8x4 double acc.
__global__ __launch_bounds__(256) void gemm_in_kernel(const float* __restrict__ A,
                                                      const float* __restrict__ B,
                                                      double* __restrict__ C) {
  __shared__ double As[16][130];   // [k][m], pad to de-conflict staging writes
  __shared__ double Bs[16][66];    // [k][n]
  const int tid = threadIdx.x;
  const int tn = tid & 15;          // n quad (fast -> coalesced C stores)
  const int tm = tid >> 4;          // m octet
  const int m0 = blockIdx.x << 7;
  const int n0 = blockIdx.y << 6;

  double acc[8][4] = {};

  for (int kt = 0; kt < 49; ++kt) {
    __syncthreads();
    // stage A: 128 rows x 16 k, 2 float4 per thread, cvt to double here
#pragma unroll
    for (int s = 0; s < 2; ++s) {
      const int idx = tid + (s << 8);       // 0..511 float4 slots
      const int row = idx >> 2;             // 0..127
      const int kc  = (idx & 3) << 2;       // 0,4,8,12
      const float4 a = *(const float4*)(A + (size_t)(m0 + row) * FDIM + kt * 16 + kc);
      As[kc + 0][row] = (double)a.x; As[kc + 1][row] = (double)a.y;
      As[kc + 2][row] = (double)a.z; As[kc + 3][row] = (double)a.w;
    }
    // stage B: 64 rows x 16 k, 1 float4 per thread
    {
      const int row = tid >> 2;             // 0..63
      const int kc  = (tid & 3) << 2;
      const float4 b = *(const float4*)(B + (size_t)(n0 + row) * FDIM + kt * 16 + kc);
      Bs[kc + 0][row] = (double)b.x; Bs[kc + 1][row] = (double)b.y;
      Bs[kc + 2][row] = (double)b.z; Bs[kc + 3][row] = (double)b.w;
    }
    __syncthreads();
#pragma unroll
    for (int kk = 0; kk < 16; ++kk) {
      double av[8], bv[4];
      *(double2*)&av[0] = *(const double2*)&As[kk][(tm << 3) + 0];
      *(double2*)&av[2] = *(const double2*)&As[kk][(tm << 3) + 2];
      *(double2*)&av[4] = *(const double2*)&As[kk][(tm << 3) + 4];
      *(double2*)&av[6] = *(const double2*)&As[kk][(tm << 3) + 6];
      *(double2*)&bv[0] = *(const double2*)&Bs[kk][(tn << 2) + 0];
      *(double2*)&bv[2] = *(const double2*)&Bs[kk][(tn << 2) + 2];
#pragma unroll
      for (int i = 0; i < 8; ++i)
#pragma unroll
        for (int j = 0; j < 4; ++j) acc[i][j] += av[i] * bv[j];
    }
  }
#pragma unroll
  for (int i = 0; i < 8; ++i) {
    double* crow = C + (size_t)(m0 + (tm << 3) + i) * HDIM + n0 + (tn << 2);
    *(double2*)(crow)     = make_double2(acc[i][0], acc[i][1]);
    *(double2*)(crow + 2) = make_double2(acc[i][2], acc[i][3]);
  }
}

// ---------------- transpose w_rec [512][512] -> wrt [k][h] ----------------
__global__ __launch_bounds__(256) void transpose_kernel(const float* __restrict__ src,
                                                        float* __restrict__ dst) {
  __shared__ float tile[32][33];
  const int bx = blockIdx.x & 15, by = blockIdx.x >> 4;
  const int tx = threadIdx.x & 31, ty = threadIdx.x >> 5;
  const int x = (bx << 5) + tx;
#pragma unroll
  for (int s = 0; s < 32; s += 8)
    tile[ty + s][tx] = src[(size_t)((by << 5) + ty + s) * HDIM + x];
  __syncthreads();
  const int xo = (by << 5) + tx;
#pragma unroll
  for (int s = 0; s < 32; s += 8)
    dst[(size_t)((bx << 5) + ty + s) * HDIM + xo] = tile[tx][ty + s];
}

// ---------------- w_out [10][512] -> wot [k][16] (cols 10..15 stay zero) -------
__global__ __launch_bounds__(256) void wot_kernel(const float* __restrict__ w_out,
                                                  float* __restrict__ wot) {
  const int k = (blockIdx.x << 8) + threadIdx.x;  // 0..511
#pragma unroll
  for (int o = 0; o < ODIM; ++o) wot[(k << 4) + o] = w_out[(size_t)o * HDIM + k];
}

// ---------------- K2: persistent LIF+LI, one block per batch element ----------
__global__ __launch_bounds__(256) void lif_kernel(const double* __restrict__ cin,
                                                  const float* __restrict__ wrt,
                                                  const float* __restrict__ wot,
                                                  float* __restrict__ out) {
  const int b = blockIdx.x;
  const int tid = threadIdx.x;
  const int h0 = tid, h1 = tid + 256;

  __shared__ unsigned long long masks[8];
  __shared__ int offs[9];                       // offs[8] = nfire (persists 1 step)
  __shared__ __align__(8) unsigned short list[528];
  __shared__ double ypart[256];

  if (tid == 0) offs[8] = 0;                    // empty list at t=0
  __syncthreads();

  double v0 = 0.0, v1 = 0.0, i0 = 0.0, i1 = 0.0;
  double lv = 0.0, li = 0.0;                    // live in threads 0..9

  const double* cinb = cin + (size_t)b * HDIM;
  float* outb = out + (size_t)b * ODIM;

  for (int t = 0; t < TT; ++t) {
    // (a) LIF: spikes from old state, then decay
    const double vd0 = v0 + DTM * ((0.0 - v0) + i0);
    const double vd1 = v1 + DTM * ((0.0 - v1) + i1);
    const bool s0 = (vd0 - 1.0) > 0.0;
    const bool s1 = (vd1 - 1.0) > 0.0;
    v0 = s0 ? 0.0 : vd0;
    v1 = s1 ? 0.0 : vd1;
    i0 = i0 - DTS * i0;
    i1 = i1 - DTS * i1;

    // issue cin loads early (consumed after gather)
    const double c0 = cinb[(size_t)t * NSTATE + h0];
    const double c1 = cinb[(size_t)t * NSTATE + h1];

    // (b) rec gather over PREVIOUS step's fired list (z(t-1) @ W_rec^T)
    {
      const int nf = offs[8];
      const int nfp = (nf + 3) & ~3;            // list padded with k=512 (zero row)
      if (nfp > 0) {
        float A0[4], A1[4], B0[4] = {}, B1[4] = {};
#define LOADG(base, X0, X1)                                                   \
        do {                                                                  \
          const unsigned long long le = *(const unsigned long long*)&list[base]; \
          const int k0 = (int)(le & 0xffffu), k1 = (int)((le >> 16) & 0xffffu); \
          const int k2 = (int)((le >> 32) & 0xffffu), k3 = (int)(le >> 48);   \
          X0[0] = wrt[(k0 << 9) + h0]; X1[0] = wrt[(k0 << 9) + h1];           \
          X0[1] = wrt[(k1 << 9) + h0]; X1[1] = wrt[(k1 << 9) + h1];           \
          X0[2] = wrt[(k2 << 9) + h0]; X1[2] = wrt[(k2 << 9) + h1];           \
          X0[3] = wrt[(k3 << 9) + h0]; X1[3] = wrt[(k3 << 9) + h1];           \
        } while (0)
        LOADG(0, A0, A1);
        for (int g = 0; g < nfp; g += 4) {
          if (g + 4 < nfp) LOADG(g + 4, B0, B1);
          i0 += (double)A0[0]; i1 += (double)A1[0];
          i0 += (double)A0[1]; i1 += (double)A1[1];
          i0 += (double)A0[2]; i1 += (double)A1[2];
          i0 += (double)A0[3]; i1 += (double)A1[3];
#pragma unroll
          for (int j = 0; j < 4; ++j) { A0[j] = B0[j]; A1[j] = B1[j]; }
        }
#undef LOADG
      }
    }
    i0 += c0;
    i1 += c1;

    __syncthreads();  // B1: gathers done reading list/offs before overwrite

    // (c) ballot + compact current spikes
    {
      const unsigned long long m0 = __ballot(s0);
      const unsigned long long m1 = __ballot(s1);
      const int w = tid >> 6;
      if ((tid & 63) == 0) { masks[w] = m0; masks[4 + w] = m1; }
    }
    __syncthreads();  // B2
    if (tid == 0) {
      int r = 0;
#pragma unroll
      for (int q = 0; q < 8; ++q) { offs[q] = r; r += __popcll(masks[q]); }
      offs[8] = r;
    }
    __syncthreads();  // B3
    if (tid < 8) {
      unsigned long long m = masks[tid];
      int o = offs[tid];
      const int base = tid << 6;
      while (m) {
        list[o++] = (unsigned short)(base + __builtin_ctzll(m));
        m &= m - 1;
      }
    }
    if (tid < 4) list[offs[8] + tid] = 512;     // pad for group-of-4 reads
    __syncthreads();  // B4

    // (d) readout y(t) = sum over current fired k of wot[k][o]
    {
      const int o = tid & 15, q = tid >> 4;     // 16 chunks x 16 "outputs" (10 real)
      const int nfc = offs[8];
      double yp = 0.0;
      int kk = q;
      if (kk < nfc) {
        float f = wot[((int)list[kk] << 4) + o];
        for (kk += 16; kk < nfc; kk += 16) {
          const float fn = wot[((int)list[kk] << 4) + o];
          yp += (double)f;
          f = fn;
        }
        yp += (double)f;
      }
      ypart[(o << 4) + q] = yp;
    }
    __syncthreads();  // B5
    if (tid < ODIM) {
      double y = 0.0;
      const double* yr = &ypart[tid << 4];
#pragma unroll
      for (int q = 0; q < 16; ++q) y += yr[q];
      const double lvn = lv + DTM * ((0.0 - lv) + li);   // uses OLD li
      li = (li - DTS * li) + y;
      lv = lvn;
      outb[(size_t)t * (BATCH * ODIM) + tid] = (float)lvn;
    }
  }
}

extern "C" void kernel_launch(void* const* d_in, const int* in_sizes, int n_in,
                              void* d_out, int out_size, void* d_ws, size_t ws_size,
                              hipStream_t stream) {
  const float* x     = (const float*)d_in[0];   // [100,512,784]
  const float* w_in  = (const float*)d_in[1];   // [512,784]
  const float* w_rec = (const float*)d_in[2];   // [512,512]
  const float* w_out = (const float*)d_in[3];   // [10,512]
  float* out = (float*)d_out;                   // [100,512,10] fp32

  const size_t CIN = (size_t)TT * BATCH * HDIM;       // 26,214,400 doubles
  double* cin = (double*)d_ws;
  float* wrt = (float*)(cin + CIN);                   // [513][512], row 512 = zeros
  float* wot = wrt + 513 * 512;                       // [513][16],  row 512 + cols 10..15 zero

  const size_t aux_floats = 513ull * 512 + 513ull * 16;
  const size_t need_bytes = CIN * sizeof(double) + aux_floats * sizeof(float);
  if (ws_size < need_bytes) {
    hipMemsetAsync(d_out, 0x7F, (size_t)out_size * sizeof(float), stream);
    return;
  }

  hipMemsetAsync(wrt, 0, aux_floats * sizeof(float), stream);
  transpose_kernel<<<256, 256, 0, stream>>>(w_rec, wrt);
  wot_kernel<<<2, 256, 0, stream>>>(w_out, wot);
  gemm_in_kernel<<<dim3(400, 8), 256, 0, stream>>>(x, w_in, cin);
  lif_kernel<<<BATCH, 256, 0, stream>>>(cin, wrt, wot, out);
}